// Round 1
// baseline (494.509 us; speedup 1.0000x reference)
//
#include <hip/hip_runtime.h>

// Problem constants (fixed by the reference): x (B,H,L) f32, k (C,H,L) f32,
// D (C,H) f32, C=1. y[b,h,l] = sum_{m<=l} x[b,h,m] k[h,l-m] + D[h] x[b,h,l].
#define Bdim 4
#define Hdim 1024
#define Ldim 4096
#define NFFT 8192            // 2*L zero-padded FFT length
#define NTHR 256
#define BPT  (NFFT / 2 / NTHR)   // butterflies per thread per stage = 16
#define EPT  (Ldim / NTHR)       // length-4096 elements per thread = 16
#define SPT  (NFFT / NTHR)       // spectrum elements per thread = 32

// v_sin_f32 / v_cos_f32 take input in REVOLUTIONS (D = sin(S0*2pi)).
__device__ __forceinline__ void sincos_rev(float f, float& s, float& c) {
#if __has_builtin(__builtin_amdgcn_sinf) && __has_builtin(__builtin_amdgcn_cosf)
    s = __builtin_amdgcn_sinf(f);
    c = __builtin_amdgcn_cosf(f);
#else
    __sincosf(f * 6.28318530717958647692f, &s, &c);
#endif
}

// Forward radix-2 DIF stages m = NFFT/2 .. 2 (stage m=NFFT is fused at load).
// Natural input -> bit-reversed output. Twiddle exp(-2*pi*i*j/m).
__device__ __forceinline__ void dif_stages(float2* A, int tid) {
    for (int m = NFFT >> 1; m >= 2; m >>= 1) {
        const int half = m >> 1;
        const float invm = 1.0f / (float)m;   // exact (power of two)
        #pragma unroll
        for (int r = 0; r < BPT; ++r) {
            int t  = tid + r * NTHR;              // butterfly id 0..4095
            int j  = t & (half - 1);
            int i1 = ((t & ~(half - 1)) << 1) | j;
            int i2 = i1 + half;
            float2 u = A[i1];
            float2 v = A[i2];
            float s, c;
            sincos_rev(-(float)j * invm, s, c);
            A[i1] = make_float2(u.x + v.x, u.y + v.y);
            float dr = u.x - v.x, di = u.y - v.y;
            A[i2] = make_float2(dr * c - di * s, dr * s + di * c);
        }
        __syncthreads();
    }
}

// Inverse radix-2 DIT stages m = 2 .. NFFT. Bit-reversed input -> natural
// output. Twiddle exp(+2*pi*i*j/m). Unnormalized (1/N folded into pointwise).
__device__ __forceinline__ void dit_stages(float2* A, int tid) {
    for (int m = 2; m <= NFFT; m <<= 1) {
        const int half = m >> 1;
        const float invm = 1.0f / (float)m;
        #pragma unroll
        for (int r = 0; r < BPT; ++r) {
            int t  = tid + r * NTHR;
            int j  = t & (half - 1);
            int i1 = ((t & ~(half - 1)) << 1) | j;
            int i2 = i1 + half;
            float s, c;
            sincos_rev((float)j * invm, s, c);
            float2 v = A[i2];
            float tr = v.x * c - v.y * s;
            float ti = v.x * s + v.y * c;
            float2 u = A[i1];
            A[i1] = make_float2(u.x + tr, u.y + ti);
            A[i2] = make_float2(u.x - tr, u.y - ti);
        }
        __syncthreads();
    }
}

__global__ __launch_bounds__(NTHR)
void fftconv_kernel(const float* __restrict__ x,
                    const float* __restrict__ kin,
                    const float* __restrict__ Din,
                    float* __restrict__ out)
{
    __shared__ float2 A[NFFT];   // 64 KiB -> 2 blocks/CU

    const int tid = threadIdx.x;
    const int blk = blockIdx.x;
    const int b = blk >> 10;            // / Hdim
    const int h = blk & (Hdim - 1);

    const float* xp = x   + ((size_t)b * Hdim + h) * (size_t)Ldim;
    const float* kp = kin + (size_t)h * (size_t)Ldim;   // C = 1
    const float  Dh = Din[h];

    const float invN = 1.0f / (float)NFFT;

    // ---- K: load + fused DIF stage m=NFFT (upper half of input is zero) ----
    // Full stage 1: A[j] = u + 0 = u ; A[j+4096] = (u-0)*exp(-2pi*i*j/NFFT).
    #pragma unroll
    for (int r = 0; r < EPT; ++r) {
        int j = tid + r * NTHR;               // 0..4095
        float v = kp[j];
        float s, c;
        sincos_rev(-(float)j * (1.0f / (float)NFFT), s, c);
        A[j]        = make_float2(v, 0.0f);
        A[j + Ldim] = make_float2(v * c, v * s);
    }
    // Load x while K's LDS init is in flight; keep for the skip term.
    float xreg[EPT];
    #pragma unroll
    for (int r = 0; r < EPT; ++r) xreg[r] = xp[tid + r * NTHR];
    __syncthreads();

    dif_stages(A, tid);                        // ends with __syncthreads()

    // Stash K spectrum (bit-reversed order) in registers: own slots only.
    float2 kspec[SPT];
    #pragma unroll
    for (int r = 0; r < SPT; ++r) kspec[r] = A[tid + r * NTHR];
    // No barrier needed: next writes touch exactly this thread's own slots.

    // ---- X: fused DIF stage 1 into the same LDS array ----
    #pragma unroll
    for (int r = 0; r < EPT; ++r) {
        int j = tid + r * NTHR;
        float v = xreg[r];
        float s, c;
        sincos_rev(-(float)j * (1.0f / (float)NFFT), s, c);
        A[j]        = make_float2(v, 0.0f);
        A[j + Ldim] = make_float2(v * c, v * s);
    }
    __syncthreads();

    dif_stages(A, tid);                        // ends with __syncthreads()

    // ---- pointwise Y = X * K / NFFT (both spectra share the bitrev order) --
    #pragma unroll
    for (int r = 0; r < SPT; ++r) {
        int p = tid + r * NTHR;                // own slots
        float2 xv = A[p];
        float2 kv = kspec[r];
        A[p] = make_float2((xv.x * kv.x - xv.y * kv.y) * invN,
                           (xv.x * kv.y + xv.y * kv.x) * invN);
    }
    __syncthreads();

    // ---- inverse FFT: bit-reversed -> natural ----
    dit_stages(A, tid);                        // ends with __syncthreads()

    // ---- epilogue: y = Re(ifft)[0:L] + D[h]*x ----
    float* op = out + ((size_t)b * Hdim + h) * (size_t)Ldim;
    #pragma unroll
    for (int r = 0; r < EPT; ++r) {
        int j = tid + r * NTHR;
        op[j] = A[j].x + xreg[r] * Dh;
    }
}

extern "C" void kernel_launch(void* const* d_in, const int* in_sizes, int n_in,
                              void* d_out, int out_size, void* d_ws, size_t ws_size,
                              hipStream_t stream)
{
    const float* x  = (const float*)d_in[0];
    const float* k  = (const float*)d_in[1];
    const float* D  = (const float*)d_in[2];
    float* out = (float*)d_out;

    dim3 grid(Bdim * Hdim);
    dim3 block(NTHR);
    hipLaunchKernelGGL(fftconv_kernel, grid, block, 0, stream, x, k, D, out);
}